// Round 3
// baseline (865.709 us; speedup 1.0000x reference)
//
#include <hip/hip_runtime.h>

// ScaleLasryLions R3: per-scale 3-stage planar pipeline, layout [b][h'][c][w].
// closing = eroH(eroW(dilW(dilH x))), opening = dilH(dilW(eroW(eroH x)))
// K1: x (interleaved) -> A=dilH, B=eroH        planar [b][h'][c][w], h' in H+2s
// K2: in-place rows: A: dilW(+k) then eroW(-kc); B: eroW(-k) then dilW(+kc). Both branches one dispatch.
// K3: xc=eroH(A), xo=dilH(B), blend, LDS transpose, write out interleaved directly.

constexpr int BB = 8, HH = 192, WW = 192, CHN = 32, SCST = 128;

constexpr float s2_of(int si) { // scale^2 for {0.25,0.75,1.75,3.75}
    return si == 0 ? 0.0625f : si == 1 ? 0.5625f : si == 2 ? 3.0625f : 14.0625f;
}
constexpr int cdiv_(int a, int b) { return (a + b - 1) / b; }

// ---------------- K1: H-pass from interleaved x -> A (dil), B (ero) ----------------
template <int SI, int SW, int NH, int MW>
__launch_bounds__(512, MW) __global__
void k_hpass1(const float* __restrict__ x, const float* __restrict__ coef,
              float* __restrict__ A, float* __restrict__ Bb) {
    constexpr int L = 2 * SW + 1, HA = HH + 2 * SW, WN = NH + 2 * SW;
    constexpr float S2 = s2_of(SI);
    const int tid = threadIdx.x;
    const int c = tid & 31, wl = tid >> 5;          // loaders: 32 c x 16 w
    const int w0 = blockIdx.x * 16;
    const int r0 = blockIdx.y * NH;
    const int b  = blockIdx.z;
    const float kmul = coef[c];

    float wb[WN];
    const float* xb = x + ((size_t)(b * HH) * WW + (w0 + wl)) * SCST + SI * CHN + c;
#pragma unroll
    for (int t = 0; t < WN; ++t) {
        int gh = r0 + t - 2 * SW;
        gh = gh < 0 ? 0 : (gh > HH - 1 ? HH - 1 : gh);
        wb[t] = xb[(size_t)gh * (WW * SCST)];
    }

    __shared__ float stg[NH][CHN][17];
    const int c2 = tid >> 4, w2 = tid & 15;         // writers: c slow, w fast

    { // dilation (+k)
        float acc[NH];
#pragma unroll
        for (int j = 0; j < L; ++j) {
            float v = (float)(j - SW);
            float tp = (-(v * v) / S2) * kmul;
#pragma unroll
            for (int o = 0; o < NH; ++o) {
                float t = wb[o + j] + tp;
                acc[o] = (j == 0) ? t : fmaxf(acc[o], t);
            }
        }
#pragma unroll
        for (int o = 0; o < NH; ++o) stg[o][c][wl] = acc[o];
    }
    __syncthreads();
#pragma unroll
    for (int o = 0; o < NH; ++o) {
        int r = r0 + o;
        if (r < HA) A[((size_t)(b * HA + r) * CHN + c2) * WW + w0 + w2] = stg[o][c2][w2];
    }
    __syncthreads();
    { // erosion (-k)
        float acc[NH];
#pragma unroll
        for (int j = 0; j < L; ++j) {
            float v = (float)(j - SW);
            float tp = (-(v * v) / S2) * kmul;
#pragma unroll
            for (int o = 0; o < NH; ++o) {
                float t = wb[o + j] - tp;
                acc[o] = (j == 0) ? t : fminf(acc[o], t);
            }
        }
#pragma unroll
        for (int o = 0; o < NH; ++o) stg[o][c][wl] = acc[o];
    }
    __syncthreads();
#pragma unroll
    for (int o = 0; o < NH; ++o) {
        int r = r0 + o;
        if (r < HA) Bb[((size_t)(b * HA + r) * CHN + c2) * WW + w0 + w2] = stg[o][c2][w2];
    }
}

// ---------------- K2: two W-passes, in-place, both branches in one dispatch ----------------
template <int SI, int SW, int BR>
__device__ __forceinline__ void wpass_body(float* __restrict__ P, const float* __restrict__ coef,
                                           const float* __restrict__ cin) {
    constexpr int L = 2 * SW + 1, WE = WW + 2 * SW;
    constexpr int NQ1 = cdiv_(WE, 32), NQ2 = WW / 32;
    constexpr float S2 = s2_of(SI);
    __shared__ float inb[8][200];
    __shared__ float tmp[8][((WE + 3) & ~3) + 4];
    const int tid = threadIdx.x;
    const int rl = tid >> 5, l = tid & 31;
    const size_t row = (size_t)blockIdx.x * 8 + rl;
    float* Prow = P + row * WW;
    const int c = (int)(row & 31);                 // layout [b][h'][c][w]
    const float k1 = coef[c], k2 = coef[c] * cin[c];

    // vector load: 48 float4 per row
#pragma unroll
    for (int i = 0; i < 2; ++i) {
        int q = l + i * 32;
        if (q < 48) ((float4*)&inb[rl][0])[q] = ((const float4*)Prow)[q];
    }
    __syncthreads();
    { // pass 1: W (clamped) -> WE, taps k1
        const int q0 = l * NQ1;
        float wbuf[NQ1 + 2 * SW];
#pragma unroll
        for (int t = 0; t < NQ1 + 2 * SW; ++t) {
            int idx = q0 + t - 2 * SW;
            idx = idx < 0 ? 0 : (idx > WW - 1 ? WW - 1 : idx);
            wbuf[t] = inb[rl][idx];
        }
        float acc[NQ1];
#pragma unroll
        for (int j = 0; j < L; ++j) {
            float v = (float)(j - SW);
            float tp = (-(v * v) / S2) * k1;
#pragma unroll
            for (int o = 0; o < NQ1; ++o) {
                float t = (BR == 0) ? wbuf[o + j] + tp : wbuf[o + j] - tp;
                acc[o] = (j == 0) ? t : ((BR == 0) ? fmaxf(acc[o], t) : fminf(acc[o], t));
            }
        }
#pragma unroll
        for (int o = 0; o < NQ1; ++o) {
            int q = q0 + o;
            if (q < WE) tmp[rl][q] = acc[o];
        }
    }
    __syncthreads();
    { // pass 2: WE -> W (VALID), opposite op, taps k2
        const int q0 = l * NQ2;
        float wbuf[NQ2 + 2 * SW];
#pragma unroll
        for (int t = 0; t < NQ2 + 2 * SW; ++t) wbuf[t] = tmp[rl][q0 + t];
        float acc[NQ2];
#pragma unroll
        for (int j = 0; j < L; ++j) {
            float v = (float)(j - SW);
            float tp = (-(v * v) / S2) * k2;
#pragma unroll
            for (int o = 0; o < NQ2; ++o) {
                float t = (BR == 0) ? wbuf[o + j] - tp : wbuf[o + j] + tp;
                acc[o] = (j == 0) ? t : ((BR == 0) ? fminf(acc[o], t) : fmaxf(acc[o], t));
            }
        }
#pragma unroll
        for (int o = 0; o < NQ2; ++o) inb[rl][q0 + o] = acc[o];
    }
    __syncthreads();
#pragma unroll
    for (int i = 0; i < 2; ++i) {
        int q = l + i * 32;
        if (q < 48) ((float4*)Prow)[q] = ((float4*)&inb[rl][0])[q];
    }
}

template <int SI, int SW>
__launch_bounds__(256, 8) __global__
void k_wpass2(float* __restrict__ A, float* __restrict__ Bb,
              const float* __restrict__ coef, const float* __restrict__ cin) {
    if (blockIdx.y == 0) wpass_body<SI, SW, 0>(A, coef, cin);
    else                 wpass_body<SI, SW, 1>(Bb, coef, cin);
}

// ---------------- K3: final H-pass + blend + interleaved store ----------------
template <int SI, int SW, int NH, int MW>
__launch_bounds__(512, MW) __global__
void k_fin3(const float* __restrict__ A, const float* __restrict__ Bb,
            const float* __restrict__ coef, const float* __restrict__ cin,
            const float* __restrict__ ain, float* __restrict__ out) {
    constexpr int L = 2 * SW + 1, HA = HH + 2 * SW, WN = NH + 2 * SW;
    constexpr float S2 = s2_of(SI);
    static_assert(HH % NH == 0, "no partial strips");
    const int tid = threadIdx.x;
    const int c = tid >> 4, w = tid & 15;           // compute: c slow, w fast (lane-contig in w)
    const int w0 = blockIdx.x * 16;
    const int h0 = blockIdx.y * NH;
    const int b  = blockIdx.z;
    const float kc = coef[c] * cin[c], av = ain[c];

    __shared__ float stg[NH][CHN][17];

    { // xc = eroH(A) with taps kc
        float wb[WN];
#pragma unroll
        for (int t = 0; t < WN; ++t)
            wb[t] = A[((size_t)(b * HA + h0 + t) * CHN + c) * WW + w0 + w];
        float acc[NH];
#pragma unroll
        for (int j = 0; j < L; ++j) {
            float v = (float)(j - SW);
            float tp = (-(v * v) / S2) * kc;
#pragma unroll
            for (int o = 0; o < NH; ++o) {
                float t = wb[o + j] - tp;
                acc[o] = (j == 0) ? t : fminf(acc[o], t);
            }
        }
#pragma unroll
        for (int o = 0; o < NH; ++o) stg[o][c][w] = acc[o];
    }
    { // xo = dilH(B) with taps kc; blend into stg
        float wb[WN];
#pragma unroll
        for (int t = 0; t < WN; ++t)
            wb[t] = Bb[((size_t)(b * HA + h0 + t) * CHN + c) * WW + w0 + w];
        float acc[NH];
#pragma unroll
        for (int j = 0; j < L; ++j) {
            float v = (float)(j - SW);
            float tp = (-(v * v) / S2) * kc;
#pragma unroll
            for (int o = 0; o < NH; ++o) {
                float t = wb[o + j] + tp;
                acc[o] = (j == 0) ? t : fmaxf(acc[o], t);
            }
        }
#pragma unroll
        for (int o = 0; o < NH; ++o)
            stg[o][c][w] = av * stg[o][c][w] + (1.0f - av) * acc[o];
    }
    __syncthreads();
    // scatter: lane = channel (contiguous 128B per (h,w) position)
    const int c2 = tid & 31, w2 = tid >> 5;         // w2 in [0,16)
    float* ob = out + SI * CHN + c2;
#pragma unroll
    for (int o = 0; o < NH; ++o)
        ob[((size_t)(b * HH + h0 + o) * WW + w0 + w2) * SCST] = stg[o][c2][w2];
}

// ---------------- Fallback: R1 fused kernel (used only if ws too small) ----------------
constexpr int r4_(int a) { return (a + 3) & ~3; }
constexpr int pickNH(int R, int C, int NT) {
    for (int nh = 1; nh <= R; ++nh)
        if (cdiv_(R, nh) * C <= NT) return nh;
    return R;
}
template <int L, int SW, int SI, bool DIL, int NH, int R, int PIT>
__device__ __forceinline__ void pass_compute_si(const float* __restrict__ in, int r0, int c,
                                                float kmul, float (&acc)[NH]) {
    constexpr float S2 = s2_of(SI);
    float wb[NH + L - 1];
#pragma unroll
    for (int t = 0; t < NH + L - 1; ++t) {
        int rr = r0 + t;
        if (rr > R + L - 2) rr = R + L - 2;
        wb[t] = in[rr * PIT + c];
    }
#pragma unroll
    for (int j = 0; j < L; ++j) {
        float v = (float)(j - SW);
        float tp = (-(v * v) / S2) * kmul;
#pragma unroll
        for (int o = 0; o < NH; ++o) {
            float t = DIL ? wb[o + j] + tp : wb[o + j] - tp;
            if (j == 0) acc[o] = t;
            else acc[o] = DIL ? fmaxf(acc[o], t) : fminf(acc[o], t);
        }
    }
}
template <int L, int SW, int SI, bool DIL, int NH, int R, int C, int PIT, int POUT, int NT>
__device__ __forceinline__ void pass_lds(const float* __restrict__ in, float* __restrict__ outT,
                                         float kmul, int tid) {
    constexpr int nseg = cdiv_(R, NH);
    for (int item = tid; item < nseg * C; item += NT) {
        int c = item % C, r0 = (item / C) * NH;
        float acc[NH];
        pass_compute_si<L, SW, SI, DIL, NH, R, PIT>(in, r0, c, kmul, acc);
#pragma unroll
        for (int o = 0; o < NH; ++o)
            if (r0 + o < R) outT[c * POUT + (r0 + o)] = acc[o];
    }
}
template <int SI, int SW, int TH, int TW, int NT, int MW>
__launch_bounds__(NT, MW) __global__
void lasry_kernel(const float* __restrict__ x, const float* __restrict__ coef,
                  const float* __restrict__ cin, const float* __restrict__ ain,
                  float* __restrict__ out) {
    constexpr int L = 2 * SW + 1;
    constexpr int IH = TH + 4 * SW, IW = TW + 4 * SW;
    constexpr int R1 = TH + 2 * SW, C1 = IW;
    constexpr int R2 = TW + 2 * SW, C2 = R1;
    constexpr int R3 = TH,          C3 = R2;
    constexpr int R4 = TW,          C4 = R3;
    constexpr int PIN = IW, PA = r4_(R1), PB = r4_(R2), PA2 = r4_(R3);
    constexpr int NH1 = pickNH(R1, C1, NT), NH2 = pickNH(R2, C2, NT);
    constexpr int NH3 = pickNH(R3, C3, NT), NH4 = pickNH(R4, C4, NT);
    __shared__ float smem[IH * PIN + C1 * PA + C2 * PB];
    float* bufIn = smem;
    float* A = smem + IH * PIN;
    float* B = A + C1 * PA;
    float* A2 = A;
    const int tid = threadIdx.x;
    const int b = blockIdx.z >> 5, ch = blockIdx.z & 31;
    const int h0 = blockIdx.y * TH, w0 = blockIdx.x * TW;
    const float kmul = coef[ch];
    const float kcmul = kmul * cin[ch];
    const float av = ain[ch];
    const float* xb = x + (size_t)(b * HH * WW) * SCST + SI * CHN + ch;
    constexpr int NLOAD = cdiv_(IH * IW, NT);
#pragma unroll
    for (int t = 0; t < NLOAD; ++t) {
        int idx = tid + t * NT;
        if (idx < IH * IW) {
            int r = idx / IW, c = idx - r * IW;
            int gh = min(max(h0 + r - 2 * SW, 0), HH - 1);
            int gw = min(max(w0 + c - 2 * SW, 0), WW - 1);
            bufIn[r * PIN + c] = xb[(size_t)(gh * WW + gw) * SCST];
        }
    }
    __syncthreads();
    const int c4 = tid % C4;
    const int r04 = (tid / C4) * NH4;
    const bool act4 = tid < cdiv_(R4, NH4) * C4;
    float xcv[NH4];
    pass_lds<L, SW, SI, true,  NH1, R1, C1, PIN, PA,  NT>(bufIn, A, kmul, tid);  __syncthreads();
    pass_lds<L, SW, SI, true,  NH2, R2, C2, PA,  PB,  NT>(A,     B, kmul, tid);  __syncthreads();
    pass_lds<L, SW, SI, false, NH3, R3, C3, PB,  PA2, NT>(B,    A2, kcmul, tid); __syncthreads();
    if (act4) pass_compute_si<L, SW, SI, false, NH4, R4, PA2>(A2, r04, c4, kcmul, xcv);
    __syncthreads();
    pass_lds<L, SW, SI, false, NH1, R1, C1, PIN, PA,  NT>(bufIn, A, kmul, tid);  __syncthreads();
    pass_lds<L, SW, SI, false, NH2, R2, C2, PA,  PB,  NT>(A,     B, kmul, tid);  __syncthreads();
    pass_lds<L, SW, SI, true,  NH3, R3, C3, PB,  PA2, NT>(B,    A2, kcmul, tid); __syncthreads();
    if (act4) {
        float xov[NH4];
        pass_compute_si<L, SW, SI, true, NH4, R4, PA2>(A2, r04, c4, kcmul, xov);
        const int h = h0 + c4;
        float* ob = out + ((size_t)(b * HH + h) * WW) * SCST + SI * CHN + ch;
#pragma unroll
        for (int o = 0; o < NH4; ++o) {
            int w = w0 + r04 + o;
            if (r04 + o < R4 && w < WW) ob[(size_t)w * SCST] = av * xcv[o] + (1.0f - av) * xov[o];
        }
    }
}

// ---------------- host ----------------
template <int SI, int SW, int NH1, int MW1, int NH3, int MW3>
static void launch_scale(const float* x, const float* coef, const float* cv, const float* av,
                         float* out, float* A, float* Bb, hipStream_t stream) {
    constexpr int HA = HH + 2 * SW;
    k_hpass1<SI, SW, NH1, MW1><<<dim3(WW / 16, cdiv_(HA, NH1), BB), 512, 0, stream>>>(x, coef, A, Bb);
    k_wpass2<SI, SW><<<dim3(BB * HA * CHN / 8, 2), 256, 0, stream>>>(A, Bb, coef, cv);
    k_fin3<SI, SW, NH3, MW3><<<dim3(WW / 16, HH / NH3, BB), 512, 0, stream>>>(A, Bb, coef, cv, av, out);
}

extern "C" void kernel_launch(void* const* d_in, const int* in_sizes, int n_in,
                              void* d_out, int out_size, void* d_ws, size_t ws_size,
                              hipStream_t stream) {
    const float* x    = (const float*)d_in[0];
    const float* coef = (const float*)d_in[1];
    const float* cv   = (const float*)d_in[2];
    const float* av   = (const float*)d_in[3];
    float* out = (float*)d_out;
    (void)in_sizes; (void)n_in; (void)out_size;

    constexpr size_t BUFSZ = (size_t)BB * 228 * CHN * WW;   // floats (s=18 extent, shared)
    constexpr size_t WS_NEED = 2 * BUFSZ * sizeof(float);   // ~89.6 MB

    if (ws_size >= WS_NEED) {
        float* A  = (float*)d_ws;
        float* Bb = A + BUFSZ;
        launch_scale<0, 1,  24, 4, 24, 4>(x, coef, cv, av, out, A, Bb, stream);
        launch_scale<1, 3,  24, 4, 24, 4>(x, coef, cv, av, out, A, Bb, stream);
        launch_scale<2, 8,  24, 3, 32, 3>(x, coef, cv, av, out, A, Bb, stream);
        launch_scale<3, 18, 24, 3, 32, 3>(x, coef, cv, av, out, A, Bb, stream);
    } else {
        lasry_kernel<0, 1, 64, 64, 1024, 8><<<dim3(3, 3, 256), 1024, 0, stream>>>(x, coef, cv, av, out);
        lasry_kernel<1, 3, 64, 64, 1024, 8><<<dim3(3, 3, 256), 1024, 0, stream>>>(x, coef, cv, av, out);
        lasry_kernel<2, 8, 64, 64, 1024, 4><<<dim3(3, 3, 256), 1024, 0, stream>>>(x, coef, cv, av, out);
        lasry_kernel<3, 18, 64, 48, 1024, 4><<<dim3(4, 3, 256), 1024, 0, stream>>>(x, coef, cv, av, out);
    }
}